// Round 15
// baseline (173.574 us; speedup 1.0000x reference)
//
#include <hip/hip_runtime.h>

#define N_NODES 100000
#define N_EDGES 1600000
#define D_IN    128
#define D_OUT   32
#define CROWS   2048                    // rows per coarse bucket
#define NCB     49                      // ceil(100000/2048)
#define NSH     8                       // shards per coarse
#define NSEG    (NCB * NSH)             // 392
#define CAP_A   4500                    // records per (coarse,shard) seg (+6.5s)
#define DEPTH   64                      // phaseA LDS depth/bin (mean 32, +5.6s)
#define SEGSTRIDE 4608                  // spk2s words per seg (18 KB, line-aligned)
#define SSTRIDE 2064                    // sseg ints per seg (2049 used, padded)
#define RPB3    64                      // rows per reduce block
#define CAPW    1536                    // merged dense words per 64-row span (+16s)
#define MERGE_BLKS (NCB * 32)           // 1568
#define GEMM_BLKS ((N_NODES + 63) / 64) // 1563
#define GEMM_A  782                     // gemm blocks co-run with phaseA
#define GEMM_B  (GEMM_BLKS - GEMM_A)    // 781, co-run with sortseg
#define GRID_A  1024                    // phaseA blocks
#define EPB_A   1564                    // edges per phaseA block (mult of 4 -> int4 ok)

typedef __attribute__((ext_vector_type(8))) short bf16x8;
typedef __attribute__((ext_vector_type(4))) float f32x4;

__device__ inline short f2bf(float f) {         // RNE float->bf16
    union { float f; unsigned u; } v; v.f = f;
    unsigned r = (v.u + 0x7FFFu + ((v.u >> 16) & 1u)) >> 16;
    return (short)r;
}

// one gather-accumulate step (identical math/order to the verified loop)
__device__ inline void gstep(const unsigned* rc, int j,
                             const unsigned short* hp, const float* __restrict__ dw1,
                             float& a0, float& a1, float& a2, float& a3)
{
    const unsigned rec = rc[j];
    const uint2 hv = *(const uint2*)(hp + ((size_t)(rec & 0x1FFFFu) << 5));
    const float w  = dw1[rec >> 20];
    a0 = fmaf(w, __uint_as_float(hv.x << 16),         a0);
    a1 = fmaf(w, __uint_as_float(hv.x & 0xFFFF0000u), a1);
    a2 = fmaf(w, __uint_as_float(hv.y << 16),         a2);
    a3 = fmaf(w, __uint_as_float(hv.y & 0xFFFF0000u), a3);
}

// ---------------------------------------------------------------------------
// gemm role body (byte-identical math to the verified baseline), shared by
// both co-kernels. wbt is the caller's 8 KB LDS region.
// ---------------------------------------------------------------------------
__device__ inline void gemm_role(const float* __restrict__ input,
                                 const float* __restrict__ W,
                                 unsigned short* __restrict__ h16,
                                 short* wbt, int gblk, int tid)
{
    for (int i = tid; i < D_IN * D_OUT; i += 256) {
        const int k = i >> 5, c = i & 31;
        wbt[c * D_IN + k] = f2bf(W[i]);
    }
    __syncthreads();

    const int wave = tid >> 6;
    const int lane = tid & 63;
    const int r0   = gblk * 64 + wave * 16;
    const int c16  = lane & 15;
    const int quad = lane >> 4;

    int ra = r0 + c16;
    if (ra >= N_NODES) ra = N_NODES - 1;
    const float* arow = input + (size_t)ra * D_IN;

    f32x4 acc0 = {0.f, 0.f, 0.f, 0.f};
    f32x4 acc1 = {0.f, 0.f, 0.f, 0.f};
#pragma unroll
    for (int q = 0; q < 4; ++q) {
        const float* ap = arow + q * 32 + quad * 8;
        f32x4 a0 = *(const f32x4*)(ap);
        f32x4 a1 = *(const f32x4*)(ap + 4);
        bf16x8 af;
        af[0] = f2bf(a0.x); af[1] = f2bf(a0.y); af[2] = f2bf(a0.z); af[3] = f2bf(a0.w);
        af[4] = f2bf(a1.x); af[5] = f2bf(a1.y); af[6] = f2bf(a1.z); af[7] = f2bf(a1.w);
        bf16x8 b0 = *(const bf16x8*)(wbt + (c16)      * D_IN + q * 32 + quad * 8);
        bf16x8 b1 = *(const bf16x8*)(wbt + (c16 + 16) * D_IN + q * 32 + quad * 8);
        acc0 = __builtin_amdgcn_mfma_f32_16x16x32_bf16(af, b0, acc0, 0, 0, 0);
        acc1 = __builtin_amdgcn_mfma_f32_16x16x32_bf16(af, b1, acc1, 0, 0, 0);
    }
#pragma unroll
    for (int i = 0; i < 4; ++i) {
        const int rr = r0 + quad * 4 + i;
        if (rr < N_NODES) {
            h16[(size_t)rr * D_OUT + c16]      = (unsigned short)f2bf(fmaxf(acc0[i], 0.f));
            h16[(size_t)rr * D_OUT + c16 + 16] = (unsigned short)f2bf(fmaxf(acc1[i], 0.f));
        }
    }
}

// ---------------------------------------------------------------------------
// K1 (phaseA ∥ gemmA): blocks [0, GRID_A) run phaseA v2 (dispatched first);
// blocks [GRID_A, +GEMM_A) run gemm rows [0, 50048). Byte-identical to r12.
// ---------------------------------------------------------------------------
union SMemPAG {
    struct { uint2 lbin[NCB][DEPTH]; int lcnt[NCB]; int gbase[NCB]; } a; // 25.5 KB
    struct { short wbt[D_IN * D_OUT]; } g;                               // 8 KB
};

__global__ __launch_bounds__(256) void phaseA_gemmA_kernel(
    const float* __restrict__ input, const float* __restrict__ W,
    const int* __restrict__ erow,    const int* __restrict__ ecol,
    const int* __restrict__ etime,
    unsigned short* __restrict__ h16,
    int* __restrict__ gcur,          // NSEG cursors, stride 16 ints
    uint2* __restrict__ segA)
{
    __shared__ SMemPAG sm;
    const int tid = threadIdx.x;

    if (blockIdx.x < GRID_A) {
        // ----------------- phaseA role v2 ---------------------------------
        const int blk   = blockIdx.x;
        const int shard = blk & (NSH - 1);
        const int wv    = tid >> 6;
        const int ln    = tid & 63;

        if (tid < NCB) sm.a.lcnt[tid] = 0;
        __syncthreads();

        const int e_beg = blk * EPB_A;                     // multiple of 4
        const int e_end = min(e_beg + EPB_A, N_EDGES);     // range size % 4 == 0

        for (int e0 = e_beg + tid * 4; e0 < e_end; e0 += 1024) {
            const int4 r4 = *(const int4*)(erow  + e0);    // 16B-aligned
            const int4 c4 = *(const int4*)(ecol  + e0);
            const int4 t4 = *(const int4*)(etime + e0);
            const int rows[4] = { r4.x, r4.y, r4.z, r4.w };
            const int cols[4] = { c4.x, c4.y, c4.z, c4.w };
            const int tms[4]  = { t4.x, t4.y, t4.z, t4.w };
            int cb[4], pos[4];
#pragma unroll
            for (int k = 0; k < 4; ++k) {                  // 4 atomics in flight
                cb[k]  = rows[k] >> 11;
                pos[k] = atomicAdd(&sm.a.lcnt[cb[k]], 1);
            }
#pragma unroll
            for (int k = 0; k < 4; ++k) {
                uint2 p;
                p.x = (unsigned)cols[k] | ((unsigned)(rows[k] & (CROWS - 1)) << 17);
                p.y = (unsigned)tms[k];
                if (pos[k] < DEPTH) sm.a.lbin[cb[k]][pos[k]] = p;
                else {  // ~5.6 sigma; correctness-safe direct write
                    const int gp = atomicAdd(&gcur[(cb[k] * NSH + shard) * 16], 1);
                    if (gp < CAP_A) segA[(size_t)(cb[k] * NSH + shard) * CAP_A + gp] = p;
                }
            }
        }
        __syncthreads();

        if (tid < NCB) {
            const int c = min(sm.a.lcnt[tid], DEPTH);
            sm.a.gbase[tid] = atomicAdd(&gcur[(tid * NSH + shard) * 16], c);
        }
        __syncthreads();

        for (int bin = wv; bin < NCB; bin += 4) {
            const int c  = min(sm.a.lcnt[bin], DEPTH);
            const int gb = sm.a.gbase[bin];
            uint2* seg = segA + (size_t)(bin * NSH + shard) * CAP_A;
            for (int k = ln; k < c; k += 64)
                if (gb + k < CAP_A) seg[gb + k] = sm.a.lbin[bin][k];
        }
    } else {
        gemm_role(input, W, h16, sm.g.wbt, blockIdx.x - GRID_A, tid);
    }
}

// ---------------------------------------------------------------------------
// K2 (sortseg ∥ gemmB): blocks [0, NSEG) run sortseg (dispatched first);
// blocks [NSEG, +GEMM_B) run gemm rows [50048, 100000). Byte-identical r12.
// ---------------------------------------------------------------------------
union SMemSSG {
    struct { int hist[CROWS]; int curs[CROWS]; int part[256]; } s;// 17 KB
    struct { short wbt[D_IN * D_OUT]; } g;                        // 8 KB
};

__global__ __launch_bounds__(256) void sortseg_gemmB_kernel(
    const float* __restrict__ input, const float* __restrict__ W,
    unsigned short* __restrict__ h16,
    const int* __restrict__ gcur, const uint2* __restrict__ segA,
    int* __restrict__ sseg, unsigned* __restrict__ spk2s)
{
    __shared__ SMemSSG sm;
    const int tid = threadIdx.x;

    if (blockIdx.x < NSEG) {
        // ----------------- sortseg role (byte-identical) ------------------
        const int b = blockIdx.x;
        const int n = min(gcur[b * 16], CAP_A);
        const uint2* seg = segA + (size_t)b * CAP_A;

        for (int t = tid; t < CROWS; t += 256) sm.s.hist[t] = 0;
        __syncthreads();

        for (int i = tid; i < n; i += 256)
            atomicAdd(&sm.s.hist[(seg[i].x >> 17) & (CROWS - 1)], 1);
        __syncthreads();

        int tmp[8]; int s0 = 0;
        const int base = tid * 8;
#pragma unroll
        for (int k = 0; k < 8; ++k) { tmp[k] = sm.s.hist[base + k]; s0 += tmp[k]; }
        sm.s.part[tid] = s0;
        __syncthreads();
        for (int off = 1; off < 256; off <<= 1) {
            int v = sm.s.part[tid];
            if (tid >= off) v += sm.s.part[tid - off];
            __syncthreads(); sm.s.part[tid] = v; __syncthreads();
        }
        int run = sm.s.part[tid] - s0;
#pragma unroll
        for (int k = 0; k < 8; ++k) { sm.s.curs[base + k] = run; run += tmp[k]; }
        __syncthreads();

        int* sg = sseg + (size_t)b * SSTRIDE;
        for (int t = tid; t < CROWS; t += 256) sg[t] = sm.s.curs[t];
        if (tid == 0) sg[CROWS] = n;
        __syncthreads();

        unsigned* dst = spk2s + (size_t)b * SEGSTRIDE;
        for (int i = tid; i < n; i += 256) {
            const uint2 p  = seg[i];
            const int   rl = (p.x >> 17) & (CROWS - 1);
            dst[atomicAdd(&sm.s.curs[rl], 1)] = (p.x & 0x1FFFFu) | (p.y << 20);
        }
    } else {
        gemm_role(input, W, h16, sm.g.wbt, GEMM_A + (int)blockIdx.x - NSEG, tid);
    }
}

// ---------------------------------------------------------------------------
// K3 (merge_reduce v3): 1568 blocks x 64 rows. Staging as r14 (verified).
// Gather now DUAL-ROW INTERLEAVED: group g processes rows g0+g and g0+g+32
// with 4+4 interleaved record steps -> 16 loads in flight per group (2x MLP)
// at identical per-row accumulation order (bit-identical output).
// ---------------------------------------------------------------------------
__global__ __launch_bounds__(256) void merge_reduce_kernel(
    const unsigned short* __restrict__ h16, const int* __restrict__ sseg,
    const unsigned* __restrict__ spk2s,
    const float* __restrict__ dw1, const float* __restrict__ dw2,
    const int* __restrict__ arrive, const int* __restrict__ obs,
    float* __restrict__ out)
{
    __shared__ int ls8[NSH][RPB3 + 1];     // 2.1 KB
    __shared__ int pre[NSH][RPB3];         // 2 KB
    __shared__ int totL[RPB3];
    __shared__ int dstart[RPB3 + 1];
    __shared__ unsigned st[CAPW];          // 6 KB

    const int b   = blockIdx.x;
    const int cb  = b >> 5;
    const int rl0 = (b & 31) * RPB3;       // row-local base within cb
    const int g0  = cb * CROWS + rl0;
    if (g0 >= N_NODES) return;
    const int tid = threadIdx.x;

    for (int t = tid; t < NSH * (RPB3 + 1); t += 256) {
        const int s = t / (RPB3 + 1), i = t - s * (RPB3 + 1);
        ls8[s][i] = sseg[(size_t)(cb * NSH + s) * SSTRIDE + rl0 + i];
    }
    __syncthreads();

    if (tid < RPB3) {
        int accp = 0;
#pragma unroll
        for (int s = 0; s < NSH; ++s) {
            pre[s][tid] = accp;
            accp += ls8[s][tid + 1] - ls8[s][tid];
        }
        totL[tid] = accp;
    }
    __syncthreads();
    if (tid == 0) {
        int runp = 0;
        for (int r = 0; r < RPB3; ++r) { dstart[r] = runp; runp += totL[r]; }
        dstart[RPB3] = runp;
    }
    __syncthreads();

    // stage NSH shard-spans into merged dense LDS (6-step binary search)
#pragma unroll
    for (int s = 0; s < NSH; ++s) {
        const int sb   = ls8[s][0];
        const int span = ls8[s][RPB3] - sb;
        const unsigned* src = spk2s + (size_t)(cb * NSH + s) * SEGSTRIDE;
        for (int i = tid; i < span; i += 256) {
            const int gidx = sb + i;
            int lo = 0, hi = RPB3 - 1;          // find r: ls8[s][r] <= gidx
#pragma unroll
            for (int it = 0; it < 6; ++it) {
                const int mid = (lo + hi + 1) >> 1;
                if (ls8[s][mid] <= gidx) lo = mid; else hi = mid - 1;
            }
            const int pos = dstart[lo] + pre[s][lo] + (gidx - ls8[s][lo]);
            if (pos < CAPW) st[pos] = src[gidx];
        }
    }
    __syncthreads();

    // dual-row interleaved gather-reduce
    const int g  = tid >> 3;               // 32 groups
    const int li = tid & 7;                // lane covers cols 4*li..4*li+3
    const int T  = 60 * obs[0];
    const unsigned short* hp = h16 + li * 4;

    const int rowA = g0 + g;               // always < N_NODES (g0+31 < N)
    const int rowB = g0 + g + 32;
    const int begA = min(dstart[g], CAPW);
    const int endA = min(dstart[g + 1], CAPW);
    const int begB = min(dstart[g + 32], CAPW);
    const int endB = min(dstart[g + 33], CAPW);
    const int nA = endA - begA;
    const int nB = (rowB < N_NODES) ? (endB - begB) : 0;
    const unsigned* rcA = &st[begA];
    const unsigned* rcB = &st[begB];

    float aA0 = 0.f, aA1 = 0.f, aA2 = 0.f, aA3 = 0.f;
    float aB0 = 0.f, aB1 = 0.f, aB2 = 0.f, aB3 = 0.f;
    int jA = 0, jB = 0;

    // joint 4+4 interleave: 16 independent gathers in the window
    while (jA + 4 <= nA && jB + 4 <= nB) {
#pragma unroll
        for (int u = 0; u < 4; ++u) gstep(rcA, jA + u, hp, dw1, aA0, aA1, aA2, aA3);
#pragma unroll
        for (int u = 0; u < 4; ++u) gstep(rcB, jB + u, hp, dw1, aB0, aB1, aB2, aB3);
        jA += 4; jB += 4;
    }
    // drain A (8-deep then scalar)
    for (; jA + 8 <= nA; jA += 8) {
#pragma unroll
        for (int u = 0; u < 8; ++u) gstep(rcA, jA + u, hp, dw1, aA0, aA1, aA2, aA3);
    }
    for (; jA < nA; ++jA) gstep(rcA, jA, hp, dw1, aA0, aA1, aA2, aA3);
    // drain B
    for (; jB + 8 <= nB; jB += 8) {
#pragma unroll
        for (int u = 0; u < 8; ++u) gstep(rcB, jB + u, hp, dw1, aB0, aB1, aB2, aB3);
    }
    for (; jB < nB; ++jB) gstep(rcB, jB, hp, dw1, aB0, aB1, aB2, aB3);

    {
        const float sdw = dw2[T - arrive[rowA] - 1];
        float4 o;
        o.x = aA0 * sdw; o.y = aA1 * sdw; o.z = aA2 * sdw; o.w = aA3 * sdw;
        *(float4*)(out + ((size_t)rowA << 5) + li * 4) = o;
    }
    if (rowB < N_NODES) {
        const float sdw = dw2[T - arrive[rowB] - 1];
        float4 o;
        o.x = aB0 * sdw; o.y = aB1 * sdw; o.z = aB2 * sdw; o.w = aB3 * sdw;
        *(float4*)(out + ((size_t)rowB << 5) + li * 4) = o;
    }
}

extern "C" void kernel_launch(void* const* d_in, const int* in_sizes, int n_in,
                              void* d_out, int out_size, void* d_ws, size_t ws_size,
                              hipStream_t stream)
{
    const float* input  = (const float*)d_in[0];
    const float* W      = (const float*)d_in[1];
    const float* dw1    = (const float*)d_in[2];
    const float* dw2    = (const float*)d_in[3];
    const int*   erow   = (const int*)d_in[4];
    const int*   ecol   = (const int*)d_in[5];
    const int*   etime  = (const int*)d_in[6];
    const int*   arrive = (const int*)d_in[7];
    const int*   obs    = (const int*)d_in[8];

    float* out = (float*)d_out;

    // Workspace (~31 MB): h16 | gcur | segA | spk2s | sseg
    char* p = (char*)d_ws;
    unsigned short* h16 = (unsigned short*)p;                 // 6.4 MB
    p += (size_t)N_NODES * D_OUT * 2;
    p = (char*)(((size_t)p + 255) & ~(size_t)255);
    int* gcur = (int*)p;                                      // 25 KB
    p += (size_t)NSEG * 16 * 4;
    p = (char*)(((size_t)p + 255) & ~(size_t)255);
    uint2* segA = (uint2*)p;                                  // 14.1 MB
    p += (size_t)NSEG * CAP_A * 8;
    p = (char*)(((size_t)p + 255) & ~(size_t)255);
    unsigned* spk2s = (unsigned*)p;                           // 7.2 MB
    p += (size_t)NSEG * SEGSTRIDE * 4;
    p = (char*)(((size_t)p + 255) & ~(size_t)255);
    int* sseg = (int*)p;                                      // 3.2 MB

    hipMemsetAsync(gcur, 0, (size_t)NSEG * 16 * 4, stream);

    phaseA_gemmA_kernel<<<GRID_A + GEMM_A, 256, 0, stream>>>(
        input, W, erow, ecol, etime, h16, gcur, segA);
    sortseg_gemmB_kernel<<<NSEG + GEMM_B, 256, 0, stream>>>(
        input, W, h16, gcur, segA, sseg, spk2s);
    merge_reduce_kernel<<<MERGE_BLKS, 256, 0, stream>>>(
        h16, sseg, spk2s, dw1, dw2, arrive, obs, out);
}

// Round 17
// 167.192 us; speedup vs baseline: 1.0382x; 1.0382x over previous
//
#include <hip/hip_runtime.h>

#define N_NODES 100000
#define N_EDGES 1600000
#define D_IN    128
#define D_OUT   32
#define CROWS   2048                    // rows per coarse bucket
#define NCB     49                      // ceil(100000/2048)
#define NSH     8                       // shards per coarse
#define NSEG    (NCB * NSH)             // 392
#define CAP_A   4500                    // records per (coarse,shard) seg (+6.5s)
#define DEPTH   64                      // phaseA LDS depth/bin (mean 32, +5.6s)
#define SEGSTRIDE 4608                  // spk2s words per seg (18 KB, line-aligned)
#define SSTRIDE 2064                    // sseg ints per seg (2049 used, padded)
#define RPB3    64                      // rows per reduce block
#define CAPW    1536                    // merged dense words per 64-row span (+16s)
#define MERGE_BLKS (NCB * 32)           // 1568
#define GEMM_BLKS ((N_NODES + 63) / 64) // 1563
#define GEMM_A  482                     // gemm blocks co-run with phaseA (rebalanced
                                        // 782->482: K2's sortseg slack absorbs more)
#define GEMM_B  (GEMM_BLKS - GEMM_A)    // 1081, co-run with sortseg
#define GRID_A  1024                    // phaseA blocks
#define EPB_A   1564                    // edges per phaseA block (mult of 4 -> int4 ok)

typedef __attribute__((ext_vector_type(8))) short bf16x8;
typedef __attribute__((ext_vector_type(4))) float f32x4;

__device__ inline short f2bf(float f) {         // RNE float->bf16
    union { float f; unsigned u; } v; v.f = f;
    unsigned r = (v.u + 0x7FFFu + ((v.u >> 16) & 1u)) >> 16;
    return (short)r;
}

// ---------------------------------------------------------------------------
// gemm role body (byte-identical math to the verified baseline), shared by
// both co-kernels. wbt is the caller's 8 KB LDS region.
// ---------------------------------------------------------------------------
__device__ inline void gemm_role(const float* __restrict__ input,
                                 const float* __restrict__ W,
                                 unsigned short* __restrict__ h16,
                                 short* wbt, int gblk, int tid)
{
    for (int i = tid; i < D_IN * D_OUT; i += 256) {
        const int k = i >> 5, c = i & 31;
        wbt[c * D_IN + k] = f2bf(W[i]);
    }
    __syncthreads();

    const int wave = tid >> 6;
    const int lane = tid & 63;
    const int r0   = gblk * 64 + wave * 16;
    const int c16  = lane & 15;
    const int quad = lane >> 4;

    int ra = r0 + c16;
    if (ra >= N_NODES) ra = N_NODES - 1;
    const float* arow = input + (size_t)ra * D_IN;

    f32x4 acc0 = {0.f, 0.f, 0.f, 0.f};
    f32x4 acc1 = {0.f, 0.f, 0.f, 0.f};
#pragma unroll
    for (int q = 0; q < 4; ++q) {
        const float* ap = arow + q * 32 + quad * 8;
        f32x4 a0 = *(const f32x4*)(ap);
        f32x4 a1 = *(const f32x4*)(ap + 4);
        bf16x8 af;
        af[0] = f2bf(a0.x); af[1] = f2bf(a0.y); af[2] = f2bf(a0.z); af[3] = f2bf(a0.w);
        af[4] = f2bf(a1.x); af[5] = f2bf(a1.y); af[6] = f2bf(a1.z); af[7] = f2bf(a1.w);
        bf16x8 b0 = *(const bf16x8*)(wbt + (c16)      * D_IN + q * 32 + quad * 8);
        bf16x8 b1 = *(const bf16x8*)(wbt + (c16 + 16) * D_IN + q * 32 + quad * 8);
        acc0 = __builtin_amdgcn_mfma_f32_16x16x32_bf16(af, b0, acc0, 0, 0, 0);
        acc1 = __builtin_amdgcn_mfma_f32_16x16x32_bf16(af, b1, acc1, 0, 0, 0);
    }
#pragma unroll
    for (int i = 0; i < 4; ++i) {
        const int rr = r0 + quad * 4 + i;
        if (rr < N_NODES) {
            h16[(size_t)rr * D_OUT + c16]      = (unsigned short)f2bf(fmaxf(acc0[i], 0.f));
            h16[(size_t)rr * D_OUT + c16 + 16] = (unsigned short)f2bf(fmaxf(acc1[i], 0.f));
        }
    }
}

// ---------------------------------------------------------------------------
// K1 (phaseA ∥ gemmA): blocks [0, GRID_A) run phaseA v2 (dispatched first);
// blocks [GRID_A, +GEMM_A) run gemm rows [0, 30848). Byte-identical bodies.
// ---------------------------------------------------------------------------
union SMemPAG {
    struct { uint2 lbin[NCB][DEPTH]; int lcnt[NCB]; int gbase[NCB]; } a; // 25.5 KB
    struct { short wbt[D_IN * D_OUT]; } g;                               // 8 KB
};

__global__ __launch_bounds__(256) void phaseA_gemmA_kernel(
    const float* __restrict__ input, const float* __restrict__ W,
    const int* __restrict__ erow,    const int* __restrict__ ecol,
    const int* __restrict__ etime,
    unsigned short* __restrict__ h16,
    int* __restrict__ gcur,          // NSEG cursors, stride 16 ints
    uint2* __restrict__ segA)
{
    __shared__ SMemPAG sm;
    const int tid = threadIdx.x;

    if (blockIdx.x < GRID_A) {
        // ----------------- phaseA role v2 ---------------------------------
        const int blk   = blockIdx.x;
        const int shard = blk & (NSH - 1);
        const int wv    = tid >> 6;
        const int ln    = tid & 63;

        if (tid < NCB) sm.a.lcnt[tid] = 0;
        __syncthreads();

        const int e_beg = blk * EPB_A;                     // multiple of 4
        const int e_end = min(e_beg + EPB_A, N_EDGES);     // range size % 4 == 0

        for (int e0 = e_beg + tid * 4; e0 < e_end; e0 += 1024) {
            const int4 r4 = *(const int4*)(erow  + e0);    // 16B-aligned
            const int4 c4 = *(const int4*)(ecol  + e0);
            const int4 t4 = *(const int4*)(etime + e0);
            const int rows[4] = { r4.x, r4.y, r4.z, r4.w };
            const int cols[4] = { c4.x, c4.y, c4.z, c4.w };
            const int tms[4]  = { t4.x, t4.y, t4.z, t4.w };
            int cb[4], pos[4];
#pragma unroll
            for (int k = 0; k < 4; ++k) {                  // 4 atomics in flight
                cb[k]  = rows[k] >> 11;
                pos[k] = atomicAdd(&sm.a.lcnt[cb[k]], 1);
            }
#pragma unroll
            for (int k = 0; k < 4; ++k) {
                uint2 p;
                p.x = (unsigned)cols[k] | ((unsigned)(rows[k] & (CROWS - 1)) << 17);
                p.y = (unsigned)tms[k];
                if (pos[k] < DEPTH) sm.a.lbin[cb[k]][pos[k]] = p;
                else {  // ~5.6 sigma; correctness-safe direct write
                    const int gp = atomicAdd(&gcur[(cb[k] * NSH + shard) * 16], 1);
                    if (gp < CAP_A) segA[(size_t)(cb[k] * NSH + shard) * CAP_A + gp] = p;
                }
            }
        }
        __syncthreads();

        if (tid < NCB) {
            const int c = min(sm.a.lcnt[tid], DEPTH);
            sm.a.gbase[tid] = atomicAdd(&gcur[(tid * NSH + shard) * 16], c);
        }
        __syncthreads();

        for (int bin = wv; bin < NCB; bin += 4) {
            const int c  = min(sm.a.lcnt[bin], DEPTH);
            const int gb = sm.a.gbase[bin];
            uint2* seg = segA + (size_t)(bin * NSH + shard) * CAP_A;
            for (int k = ln; k < c; k += 64)
                if (gb + k < CAP_A) seg[gb + k] = sm.a.lbin[bin][k];
        }
    } else {
        gemm_role(input, W, h16, sm.g.wbt, blockIdx.x - GRID_A, tid);
    }
}

// ---------------------------------------------------------------------------
// K2 (sortseg ∥ gemmB): blocks [0, NSEG) run sortseg (dispatched first);
// blocks [NSEG, +GEMM_B) run gemm rows [30848, 100000). Byte-identical.
// ---------------------------------------------------------------------------
union SMemSSG {
    struct { int hist[CROWS]; int curs[CROWS]; int part[256]; } s;// 17 KB
    struct { short wbt[D_IN * D_OUT]; } g;                        // 8 KB
};

__global__ __launch_bounds__(256) void sortseg_gemmB_kernel(
    const float* __restrict__ input, const float* __restrict__ W,
    unsigned short* __restrict__ h16,
    const int* __restrict__ gcur, const uint2* __restrict__ segA,
    int* __restrict__ sseg, unsigned* __restrict__ spk2s)
{
    __shared__ SMemSSG sm;
    const int tid = threadIdx.x;

    if (blockIdx.x < NSEG) {
        // ----------------- sortseg role (byte-identical) ------------------
        const int b = blockIdx.x;
        const int n = min(gcur[b * 16], CAP_A);
        const uint2* seg = segA + (size_t)b * CAP_A;

        for (int t = tid; t < CROWS; t += 256) sm.s.hist[t] = 0;
        __syncthreads();

        for (int i = tid; i < n; i += 256)
            atomicAdd(&sm.s.hist[(seg[i].x >> 17) & (CROWS - 1)], 1);
        __syncthreads();

        int tmp[8]; int s0 = 0;
        const int base = tid * 8;
#pragma unroll
        for (int k = 0; k < 8; ++k) { tmp[k] = sm.s.hist[base + k]; s0 += tmp[k]; }
        sm.s.part[tid] = s0;
        __syncthreads();
        for (int off = 1; off < 256; off <<= 1) {
            int v = sm.s.part[tid];
            if (tid >= off) v += sm.s.part[tid - off];
            __syncthreads(); sm.s.part[tid] = v; __syncthreads();
        }
        int run = sm.s.part[tid] - s0;
#pragma unroll
        for (int k = 0; k < 8; ++k) { sm.s.curs[base + k] = run; run += tmp[k]; }
        __syncthreads();

        int* sg = sseg + (size_t)b * SSTRIDE;
        for (int t = tid; t < CROWS; t += 256) sg[t] = sm.s.curs[t];
        if (tid == 0) sg[CROWS] = n;
        __syncthreads();

        unsigned* dst = spk2s + (size_t)b * SEGSTRIDE;
        for (int i = tid; i < n; i += 256) {
            const uint2 p  = seg[i];
            const int   rl = (p.x >> 17) & (CROWS - 1);
            dst[atomicAdd(&sm.s.curs[rl], 1)] = (p.x & 0x1FFFFu) | (p.y << 20);
        }
    } else {
        gemm_role(input, W, h16, sm.g.wbt, GEMM_A + (int)blockIdx.x - NSEG, tid);
    }
}

// ---------------------------------------------------------------------------
// K3 (merge_reduce, r14-verified): 1568 blocks x 64 rows. Staging with 6-step
// binary search; single-row-per-group 8-deep gather (dual-row interleave was
// null/regression in r15 -> gather is memory-throughput-bound, keep simple).
// ---------------------------------------------------------------------------
__global__ __launch_bounds__(256) void merge_reduce_kernel(
    const unsigned short* __restrict__ h16, const int* __restrict__ sseg,
    const unsigned* __restrict__ spk2s,
    const float* __restrict__ dw1, const float* __restrict__ dw2,
    const int* __restrict__ arrive, const int* __restrict__ obs,
    float* __restrict__ out)
{
    __shared__ int ls8[NSH][RPB3 + 1];     // 2.1 KB
    __shared__ int pre[NSH][RPB3];         // 2 KB
    __shared__ int totL[RPB3];
    __shared__ int dstart[RPB3 + 1];
    __shared__ unsigned st[CAPW];          // 6 KB

    const int b   = blockIdx.x;
    const int cb  = b >> 5;
    const int rl0 = (b & 31) * RPB3;       // row-local base within cb
    const int g0  = cb * CROWS + rl0;
    if (g0 >= N_NODES) return;
    const int tid = threadIdx.x;

    for (int t = tid; t < NSH * (RPB3 + 1); t += 256) {
        const int s = t / (RPB3 + 1), i = t - s * (RPB3 + 1);
        ls8[s][i] = sseg[(size_t)(cb * NSH + s) * SSTRIDE + rl0 + i];
    }
    __syncthreads();

    if (tid < RPB3) {
        int accp = 0;
#pragma unroll
        for (int s = 0; s < NSH; ++s) {
            pre[s][tid] = accp;
            accp += ls8[s][tid + 1] - ls8[s][tid];
        }
        totL[tid] = accp;
    }
    __syncthreads();
    if (tid == 0) {
        int runp = 0;
        for (int r = 0; r < RPB3; ++r) { dstart[r] = runp; runp += totL[r]; }
        dstart[RPB3] = runp;
    }
    __syncthreads();

    // stage NSH shard-spans into merged dense LDS (6-step binary search)
#pragma unroll
    for (int s = 0; s < NSH; ++s) {
        const int sb   = ls8[s][0];
        const int span = ls8[s][RPB3] - sb;
        const unsigned* src = spk2s + (size_t)(cb * NSH + s) * SEGSTRIDE;
        for (int i = tid; i < span; i += 256) {
            const int gidx = sb + i;
            int lo = 0, hi = RPB3 - 1;          // find r: ls8[s][r] <= gidx
#pragma unroll
            for (int it = 0; it < 6; ++it) {
                const int mid = (lo + hi + 1) >> 1;
                if (ls8[s][mid] <= gidx) lo = mid; else hi = mid - 1;
            }
            const int pos = dstart[lo] + pre[s][lo] + (gidx - ls8[s][lo]);
            if (pos < CAPW) st[pos] = src[gidx];
        }
    }
    __syncthreads();

    // verified dense gather-reduce; group g handles rows g0+g and g0+g+32
    const int g  = tid >> 3;               // 32 groups
    const int li = tid & 7;                // lane covers cols 4*li..4*li+3
    const int T  = 60 * obs[0];
    const unsigned short* hp = h16 + li * 4;

    for (int rsub = g; rsub < RPB3; rsub += 32) {
        const int row = g0 + rsub;
        if (row >= N_NODES) break;         // partial tail window only
        const int begc = min(dstart[rsub], CAPW);
        const int endc = min(dstart[rsub + 1], CAPW);
        const int n    = endc - begc;
        const unsigned* recs = &st[begc];

        float a0 = 0.f, a1 = 0.f, a2 = 0.f, a3 = 0.f;
        int j = 0;
        for (; j + 8 <= n; j += 8) {
#pragma unroll
            for (int u = 0; u < 8; ++u) {
                const unsigned rec = recs[j + u];
                const uint2 hv = *(const uint2*)(hp + ((size_t)(rec & 0x1FFFFu) << 5));
                const float w  = dw1[rec >> 20];
                a0 = fmaf(w, __uint_as_float(hv.x << 16),         a0);
                a1 = fmaf(w, __uint_as_float(hv.x & 0xFFFF0000u), a1);
                a2 = fmaf(w, __uint_as_float(hv.y << 16),         a2);
                a3 = fmaf(w, __uint_as_float(hv.y & 0xFFFF0000u), a3);
            }
        }
        for (; j < n; ++j) {
            const unsigned rec = recs[j];
            const uint2 hv = *(const uint2*)(hp + ((size_t)(rec & 0x1FFFFu) << 5));
            const float w  = dw1[rec >> 20];
            a0 = fmaf(w, __uint_as_float(hv.x << 16),         a0);
            a1 = fmaf(w, __uint_as_float(hv.x & 0xFFFF0000u), a1);
            a2 = fmaf(w, __uint_as_float(hv.y << 16),         a2);
            a3 = fmaf(w, __uint_as_float(hv.y & 0xFFFF0000u), a3);
        }

        const float sdw = dw2[T - arrive[row] - 1];
        float4 o;
        o.x = a0 * sdw; o.y = a1 * sdw; o.z = a2 * sdw; o.w = a3 * sdw;
        *(float4*)(out + ((size_t)row << 5) + li * 4) = o;
    }
}

extern "C" void kernel_launch(void* const* d_in, const int* in_sizes, int n_in,
                              void* d_out, int out_size, void* d_ws, size_t ws_size,
                              hipStream_t stream)
{
    const float* input  = (const float*)d_in[0];
    const float* W      = (const float*)d_in[1];
    const float* dw1    = (const float*)d_in[2];
    const float* dw2    = (const float*)d_in[3];
    const int*   erow   = (const int*)d_in[4];
    const int*   ecol   = (const int*)d_in[5];
    const int*   etime  = (const int*)d_in[6];
    const int*   arrive = (const int*)d_in[7];
    const int*   obs    = (const int*)d_in[8];

    float* out = (float*)d_out;

    // Workspace (~31 MB): h16 | gcur | segA | spk2s | sseg
    char* p = (char*)d_ws;
    unsigned short* h16 = (unsigned short*)p;                 // 6.4 MB
    p += (size_t)N_NODES * D_OUT * 2;
    p = (char*)(((size_t)p + 255) & ~(size_t)255);
    int* gcur = (int*)p;                                      // 25 KB
    p += (size_t)NSEG * 16 * 4;
    p = (char*)(((size_t)p + 255) & ~(size_t)255);
    uint2* segA = (uint2*)p;                                  // 14.1 MB
    p += (size_t)NSEG * CAP_A * 8;
    p = (char*)(((size_t)p + 255) & ~(size_t)255);
    unsigned* spk2s = (unsigned*)p;                           // 7.2 MB
    p += (size_t)NSEG * SEGSTRIDE * 4;
    p = (char*)(((size_t)p + 255) & ~(size_t)255);
    int* sseg = (int*)p;                                      // 3.2 MB

    hipMemsetAsync(gcur, 0, (size_t)NSEG * 16 * 4, stream);

    phaseA_gemmA_kernel<<<GRID_A + GEMM_A, 256, 0, stream>>>(
        input, W, erow, ecol, etime, h16, gcur, segA);
    sortseg_gemmB_kernel<<<NSEG + GEMM_B, 256, 0, stream>>>(
        input, W, h16, gcur, segA, sseg, spk2s);
    merge_reduce_kernel<<<MERGE_BLKS, 256, 0, stream>>>(
        h16, sseg, spk2s, dw1, dw2, arrive, obs, out);
}